// Round 4
// baseline (518.132 us; speedup 1.0000x reference)
//
#include <hip/hip_runtime.h>
#include <math.h>

#define NN 50000
#define RR 32
#define HH 16
#define CC 8
#define SHIFT 6
#define BSZ (1 << SHIFT)                 // 64 dsts per bucket
#define NB ((NN + BSZ - 1) >> SHIFT)     // 782 buckets
#define G 256                            // hist/scatter blocks
#define TSTR 17                          // accum1 tile stride (bank spread)
#define OSTR 9                           // accum2 otile stride

__device__ __forceinline__ float dot4(float4 a, float4 b) {
    return a.x * b.x + a.y * b.y + a.z * b.z + a.w * b.w;
}

// ---------------- phase 0: per-(d,r) counts -> inv ----------------

__global__ void count_k(const int* __restrict__ et, const int* __restrict__ dst,
                        float* __restrict__ cnt, int E) {
    int i = blockIdx.x * blockDim.x + threadIdx.x;
    if (i < E) atomicAdd(&cnt[dst[i] * RR + et[i]], 1.0f);
}

__global__ void inv_k(float* __restrict__ cnt, int n) {
    int i = blockIdx.x * blockDim.x + threadIdx.x;
    if (i < n) cnt[i] = 1.0f / fmaxf(cnt[i], 1.0f);
}

// ---------------- phase 1: bucket edges by dst>>SHIFT ----------------

__global__ void hist_k(const int* __restrict__ dst, int* __restrict__ hist, int E) {
    __shared__ int lh[NB];
    int g = blockIdx.x, tid = threadIdx.x;
    for (int j = tid; j < NB; j += 256) lh[j] = 0;
    __syncthreads();
    int chunk = (E + G - 1) / G;
    int beg = g * chunk, end = min(beg + chunk, E);
    for (int i = beg + tid; i < end; i += 256)
        atomicAdd(&lh[dst[i] >> SHIFT], 1);
    __syncthreads();
    for (int j = tid; j < NB; j += 256) hist[g * NB + j] = lh[j];
}

__global__ void scan2_k(const int* __restrict__ hist, int* __restrict__ pos,
                        int* __restrict__ boff, int E) {
    __shared__ int lds[1024];
    int b = threadIdx.x;
    int total = 0;
    if (b < NB)
        for (int g = 0; g < G; ++g) total += hist[g * NB + b];
    lds[b] = (b < NB) ? total : 0;
    __syncthreads();
    for (int ofs = 1; ofs < 1024; ofs <<= 1) {
        int add = (b >= ofs) ? lds[b - ofs] : 0;
        __syncthreads();
        lds[b] += add;
        __syncthreads();
    }
    if (b < NB) {
        int base = lds[b] - total;
        boff[b] = base;
        int run = base;
        for (int g = 0; g < G; ++g) { pos[g * NB + b] = run; run += hist[g * NB + b]; }
    }
    if (b == 0) boff[NB] = E;
}

// rec = s | r<<16 | dl<<21 ; also perm[i] = bucketed position (if perm != null)
__global__ void scatter2_k(const int* __restrict__ src, const int* __restrict__ dst,
                           const int* __restrict__ et, const int* __restrict__ pos,
                           unsigned* __restrict__ bucket, int* __restrict__ perm, int E) {
    __shared__ int cur[NB];
    int g = blockIdx.x, tid = threadIdx.x;
    for (int j = tid; j < NB; j += 256) cur[j] = pos[g * NB + j];
    __syncthreads();
    int chunk = (E + G - 1) / G;
    int beg = g * chunk, end = min(beg + chunk, E);
    for (int i = beg + tid; i < end; i += 256) {
        int d = dst[i];
        int bk = d >> SHIFT;
        int p = atomicAdd(&cur[bk], 1);
        bucket[p] = (unsigned)src[i] | ((unsigned)et[i] << 16) |
                    ((unsigned)(d & (BSZ - 1)) << 21);
        if (perm) perm[i] = p;
    }
}

// ---------------- layer 1 (main path): gather + bucketed accumulate ----------------

// one lane per edge, original (relation-sorted) order: max MLP, full-line 64B stores
__global__ __launch_bounds__(256) void gather1_k(
        const int* __restrict__ src, const int* __restrict__ dst,
        const int* __restrict__ et, const int* __restrict__ perm,
        const float* __restrict__ inv, const float4* __restrict__ w1v,
        float4* __restrict__ msg, int E) {
    int stride = gridDim.x * blockDim.x;
#pragma unroll 2
    for (int e = blockIdx.x * blockDim.x + threadIdx.x; e < E; e += stride) {
        int s = src[e], d = dst[e], r = et[e], p = perm[e];
        float sc = inv[d * RR + r];
        const float4* wr = w1v + (size_t)(r * NN + s) * 4;
        float4 a = wr[0], b = wr[1], c = wr[2], q = wr[3];
        float4* mr = msg + (size_t)p * 4;
        mr[0] = make_float4(a.x * sc, a.y * sc, a.z * sc, a.w * sc);
        mr[1] = make_float4(b.x * sc, b.y * sc, b.z * sc, b.w * sc);
        mr[2] = make_float4(c.x * sc, c.y * sc, c.z * sc, c.w * sc);
        mr[3] = make_float4(q.x * sc, q.y * sc, q.z * sc, q.w * sc);
    }
}

// per-bucket: sequential msg read -> LDS tile -> h = relu(tile + root1 + bias1)
__global__ __launch_bounds__(512) void accum1_k(
        const unsigned* __restrict__ bucket, const int* __restrict__ boff,
        const float4* __restrict__ msg, const float* __restrict__ root1,
        const float* __restrict__ bias1, float* __restrict__ h) {
    __shared__ float tile[BSZ * TSTR];
    int b = blockIdx.x, tid = threadIdx.x;
    for (int j = tid; j < BSZ * TSTR; j += 512) tile[j] = 0.f;
    __syncthreads();
    int e0 = boff[b], n = boff[b + 1] - e0;
    int d0 = b << SHIFT;
    int ndst = NN - d0; if (ndst > BSZ) ndst = BSZ;
#pragma unroll 2
    for (int i = tid; i < n * 4; i += 512) {
        int e = i >> 2, q = i & 3;
        unsigned rec = bucket[e0 + e];
        int dl = rec >> 21;
        float4 m = msg[(size_t)(e0 + e) * 4 + q];
        float* t = &tile[dl * TSTR + q * 4];
        atomicAdd(t + 0, m.x); atomicAdd(t + 1, m.y);
        atomicAdd(t + 2, m.z); atomicAdd(t + 3, m.w);
    }
    __syncthreads();
    for (int j = tid; j < ndst * HH; j += 512) {
        int dl = j >> 4, ch = j & 15;
        int d = d0 + dl;
        float v = tile[dl * TSTR + ch] + root1[d * HH + ch] + bias1[ch];
        h[d * HH + ch] = fmaxf(v, 0.f);
    }
}

// ---------------- layer 1 (fallback path, small ws): global atomics ----------------

__global__ void fb_l1_k(const int* __restrict__ src, const int* __restrict__ dst,
                        const int* __restrict__ et, const float* __restrict__ w1,
                        const float* __restrict__ inv, float* __restrict__ h, int E) {
    int total = E * HH;
    int stride = gridDim.x * blockDim.x;
    for (int t = blockIdx.x * blockDim.x + threadIdx.x; t < total; t += stride) {
        int e = t >> 4, i = t & 15;
        int r = et[e], s = src[e], d = dst[e];
        atomicAdd(&h[d * HH + i], w1[(r * NN + s) * HH + i] * inv[d * RR + r]);
    }
}

__global__ void hfin_k(float* __restrict__ h, const float* __restrict__ root1,
                       const float* __restrict__ bias1) {
    int t = blockIdx.x * blockDim.x + threadIdx.x;
    if (t < NN * HH) h[t] = fmaxf(h[t] + root1[t] + bias1[t & 15], 0.0f);
}

// ---------------- layer 2: per-bucket gather + fused epilogue ----------------
// w2q LDS layout: float4 element (r, c, f4) at [r*33 + c*4 + f4]; r-stride 33 spreads banks

__global__ __launch_bounds__(512) void accum2_k(
        const unsigned* __restrict__ bucket, const int* __restrict__ boff,
        const float* __restrict__ inv, const float* __restrict__ h,
        const float* __restrict__ w2, const float* __restrict__ root2,
        const float* __restrict__ bias2, float* __restrict__ out) {
    __shared__ float4 w2q[RR * 33];          // 16.9 KB
    __shared__ float otile[BSZ * OSTR];      // 2.3 KB
    int b = blockIdx.x, tid = threadIdx.x;
    for (int j = tid; j < RR * CC * 4; j += 512) {
        int r = j >> 5, c = (j >> 2) & 7, f4 = j & 3;
        const float* wb = w2 + r * HH * CC + f4 * 4 * CC + c;
        w2q[r * 33 + c * 4 + f4] = make_float4(wb[0], wb[CC], wb[2 * CC], wb[3 * CC]);
    }
    for (int j = tid; j < BSZ * OSTR; j += 512) otile[j] = 0.f;
    __syncthreads();
    int e0 = boff[b], n = boff[b + 1] - e0;
    int d0 = b << SHIFT;
    int ndst = NN - d0; if (ndst > BSZ) ndst = BSZ;
#pragma unroll 2
    for (int i = tid; i < n * 2; i += 512) {
        int e = i >> 1, c0 = (i & 1) * 4;
        unsigned rec = bucket[e0 + e];
        int s = rec & 0xFFFF;
        int r = (rec >> 16) & 31;
        int dl = rec >> 21;
        float sc = inv[(d0 + dl) * RR + r];
        const float4* hv = (const float4*)(h + s * HH);
        float4 h0 = hv[0], h1 = hv[1], h2 = hv[2], h3 = hv[3];
        const float4* wq = &w2q[r * 33 + c0 * 4];
        float acc[4];
#pragma unroll
        for (int cc = 0; cc < 4; ++cc) {
            acc[cc] = dot4(h0, wq[cc * 4 + 0]) + dot4(h1, wq[cc * 4 + 1]) +
                      dot4(h2, wq[cc * 4 + 2]) + dot4(h3, wq[cc * 4 + 3]);
        }
        float* t = &otile[dl * OSTR + c0];
        atomicAdd(t + 0, acc[0] * sc); atomicAdd(t + 1, acc[1] * sc);
        atomicAdd(t + 2, acc[2] * sc); atomicAdd(t + 3, acc[3] * sc);
    }
    __syncthreads();
    for (int dl = tid; dl < ndst; dl += 512) {
        int d = d0 + dl;
        const float4* hv = (const float4*)(h + d * HH);
        float4 h0 = hv[0], h1 = hv[1], h2 = hv[2], h3 = hv[3];
        float hr[16] = {h0.x, h0.y, h0.z, h0.w, h1.x, h1.y, h1.z, h1.w,
                        h2.x, h2.y, h2.z, h2.w, h3.x, h3.y, h3.z, h3.w};
        float v[CC];
#pragma unroll
        for (int c = 0; c < CC; ++c) {
            float a = otile[dl * OSTR + c] + bias2[c];
#pragma unroll
            for (int f = 0; f < HH; ++f) a += hr[f] * root2[f * CC + c];
            v[c] = a;
        }
        float m = v[0];
#pragma unroll
        for (int c = 1; c < CC; ++c) m = fmaxf(m, v[c]);
        float ssum = 0.f;
#pragma unroll
        for (int c = 0; c < CC; ++c) ssum += expf(v[c] - m);
        float l = logf(ssum);
#pragma unroll
        for (int c = 0; c < CC; ++c) out[d * CC + c] = v[c] - m - l;
    }
}

// ---------------- launch ----------------

extern "C" void kernel_launch(void* const* d_in, const int* in_sizes, int n_in,
                              void* d_out, int out_size, void* d_ws, size_t ws_size,
                              hipStream_t stream) {
    const int*   edge_index = (const int*)d_in[0];
    const int*   edge_type  = (const int*)d_in[1];
    const float* weight1    = (const float*)d_in[2];
    const float* root1      = (const float*)d_in[3];
    const float* bias1      = (const float*)d_in[4];
    const float* weight2    = (const float*)d_in[5];
    const float* root2      = (const float*)d_in[6];
    const float* bias2      = (const float*)d_in[7];
    float* out = (float*)d_out;

    const int E = in_sizes[1];
    const int* src = edge_index;
    const int* dst = edge_index + E;

    char* p = (char*)d_ws;
    auto alloc = [&](size_t bytes) -> void* {
        void* r = (void*)p; p += (bytes + 255) & ~(size_t)255; return r;
    };
    float*    cnt    = (float*)   alloc(sizeof(float) * (size_t)NN * RR);
    int*      hist   = (int*)     alloc(sizeof(int) * (size_t)G * NB);
    int*      pos    = (int*)     alloc(sizeof(int) * (size_t)G * NB);
    int*      boff   = (int*)     alloc(sizeof(int) * (NB + 1));
    unsigned* bucket = (unsigned*)alloc(sizeof(unsigned) * (size_t)E);
    float*    h      = (float*)   alloc(sizeof(float) * (size_t)NN * HH);
    int*      perm   = (int*)     alloc(sizeof(int) * (size_t)E);
    float4*   msg    = (float4*)  alloc(sizeof(float4) * (size_t)E * 4);
    size_t main_need = (size_t)(p - (char*)d_ws);
    bool main_path = ws_size >= main_need;

    hipMemsetAsync(cnt, 0, sizeof(float) * (size_t)NN * RR, stream);

    const int B = 256;
    count_k<<<(E + B - 1) / B, B, 0, stream>>>(edge_type, dst, cnt, E);
    inv_k<<<(NN * RR + B - 1) / B, B, 0, stream>>>(cnt, NN * RR);

    hist_k<<<G, B, 0, stream>>>(dst, hist, E);
    scan2_k<<<1, 1024, 0, stream>>>(hist, pos, boff, E);
    scatter2_k<<<G, B, 0, stream>>>(src, dst, edge_type, pos, bucket,
                                    main_path ? perm : (int*)nullptr, E);

    if (main_path) {
        gather1_k<<<2048, 256, 0, stream>>>(src, dst, edge_type, perm, cnt,
                                            (const float4*)weight1, msg, E);
        accum1_k<<<NB, 512, 0, stream>>>(bucket, boff, msg, root1, bias1, h);
    } else {
        hipMemsetAsync(h, 0, sizeof(float) * (size_t)NN * HH, stream);
        fb_l1_k<<<4096, B, 0, stream>>>(src, dst, edge_type, weight1, cnt, h, E);
        hfin_k<<<(NN * HH + B - 1) / B, B, 0, stream>>>(h, root1, bias1);
    }

    accum2_k<<<NB, 512, 0, stream>>>(bucket, boff, cnt, h, weight2, root2, bias2, out);
}

// Round 5
// 147.978 us; speedup vs baseline: 3.5014x; 3.5014x over previous
//
#include <hip/hip_runtime.h>
#include <math.h>

#define NN 50000
#define RR 32
#define HH 16
#define CC 8
#define SHIFT 6
#define BSZ 64                       // dsts per bucket
#define NB 782                       // ceil(NN/BSZ)
#define G 256                        // hist/scatter blocks
#define BINS (BSZ * RR)              // 2048 per-bucket (dl,r) bins
#define STAGE_MAX 4096

// ---------------- phase 1: bucket edges by dst>>SHIFT ----------------

__global__ void hist_k(const int* __restrict__ dst, int* __restrict__ hist, int E) {
    __shared__ int lh[NB];
    int g = blockIdx.x, tid = threadIdx.x;
    for (int j = tid; j < NB; j += 256) lh[j] = 0;
    __syncthreads();
    int chunk = (E + G - 1) / G;
    int beg = g * chunk, end = min(beg + chunk, E);
    for (int i = beg + tid; i < end; i += 256)
        atomicAdd(&lh[dst[i] >> SHIFT], 1);
    __syncthreads();
    for (int j = tid; j < NB; j += 256) hist[g * NB + j] = lh[j];
}

// btot[b] = sum_g hist[g][b]
__global__ void scanA_k(const int* __restrict__ hist, int* __restrict__ btot) {
    __shared__ int red[4];
    int b = blockIdx.x, t = threadIdx.x;
    int v = hist[t * NB + b];
#pragma unroll
    for (int m = 1; m < 64; m <<= 1) v += __shfl_xor(v, m);
    if ((t & 63) == 0) red[t >> 6] = v;
    __syncthreads();
    if (t == 0) btot[b] = red[0] + red[1] + red[2] + red[3];
}

// exclusive scan of btot -> boff
__global__ void scanB_k(const int* __restrict__ btot, int* __restrict__ boff) {
    __shared__ int lds[1024];
    int t = threadIdx.x;
    int v = (t < NB) ? btot[t] : 0;
    lds[t] = v;
    __syncthreads();
    for (int ofs = 1; ofs < 1024; ofs <<= 1) {
        int add = (t >= ofs) ? lds[t - ofs] : 0;
        __syncthreads();
        lds[t] += add;
        __syncthreads();
    }
    if (t < NB) boff[t] = lds[t] - v;
    if (t == NB - 1) boff[NB] = lds[t];
}

// pos[g][b] = boff[b] + exclusive-prefix over g
__global__ void scanC_k(const int* __restrict__ hist, const int* __restrict__ boff,
                        int* __restrict__ pos) {
    __shared__ int lds[256];
    int b = blockIdx.x, t = threadIdx.x;
    int v = hist[t * NB + b];
    lds[t] = v;
    __syncthreads();
    for (int ofs = 1; ofs < 256; ofs <<= 1) {
        int add = (t >= ofs) ? lds[t - ofs] : 0;
        __syncthreads();
        lds[t] += add;
        __syncthreads();
    }
    pos[t * NB + b] = boff[b] + lds[t] - v;
}

// rec = s | r<<16 | dl<<21
__global__ void scatter2_k(const int* __restrict__ src, const int* __restrict__ dst,
                           const int* __restrict__ et, const int* __restrict__ pos,
                           unsigned* __restrict__ bucket, int E) {
    __shared__ int cur[NB];
    int g = blockIdx.x, tid = threadIdx.x;
    for (int j = tid; j < NB; j += 256) cur[j] = pos[g * NB + j];
    __syncthreads();
    int chunk = (E + G - 1) / G;
    int beg = g * chunk, end = min(beg + chunk, E);
    for (int i = beg + tid; i < end; i += 256) {
        int d = dst[i];
        int p = atomicAdd(&cur[d >> SHIFT], 1);
        bucket[p] = (unsigned)src[i] | ((unsigned)et[i] << 16) |
                    ((unsigned)(d & (BSZ - 1)) << 21);
    }
}

// ---------------- phase 2: per-bucket counting sort by (dl,r) ----------------
// outputs: sorted recs (s|r<<16), off[d] segment starts, inv[d*RR+r] from bin counts

__global__ __launch_bounds__(256) void sortfin_k(
        const unsigned* __restrict__ bucket, const int* __restrict__ boff,
        unsigned* __restrict__ sorted, int* __restrict__ off, float* __restrict__ inv) {
    __shared__ int bins[BINS];
    __shared__ unsigned stage[STAGE_MAX];
    __shared__ int ts[256];
    int b = blockIdx.x, t = threadIdx.x;
    int e0 = boff[b], n = boff[b + 1] - e0;
    int d0 = b * BSZ;
    int ndst = NN - d0; if (ndst > BSZ) ndst = BSZ;
    for (int j = t; j < BINS; j += 256) bins[j] = 0;
    __syncthreads();
    for (int i = t; i < n; i += 256) {
        unsigned rec = bucket[e0 + i];
        int key = ((rec >> 21) & 63) * RR + ((rec >> 16) & 31);
        atomicAdd(&bins[key], 1);
    }
    __syncthreads();
    // inv from bin counts (before scan overwrites bins)
    for (int j = t; j < ndst * RR; j += 256)
        inv[d0 * RR + j] = 1.0f / fmaxf((float)bins[j], 1.0f);
    // block-exclusive scan over 2048 bins (8 per thread)
    int loc[8]; int s = 0;
#pragma unroll
    for (int k = 0; k < 8; ++k) { loc[k] = bins[t * 8 + k]; s += loc[k]; }
    ts[t] = s;
    __syncthreads();
    for (int ofs = 1; ofs < 256; ofs <<= 1) {
        int add = (t >= ofs) ? ts[t - ofs] : 0;
        __syncthreads();
        ts[t] += add;
        __syncthreads();
    }
    int run = ts[t] - s;
    __syncthreads();
#pragma unroll
    for (int k = 0; k < 8; ++k) { int c = loc[k]; bins[t * 8 + k] = run; run += c; }
    __syncthreads();
    // per-dst segment starts
    for (int dl = t; dl < ndst; dl += 256) off[d0 + dl] = e0 + bins[dl * RR];
    if (b == NB - 1 && t == 0) off[NN] = e0 + n;
    __syncthreads();
    // scatter to sorted order
    if (n <= STAGE_MAX) {
        for (int i = t; i < n; i += 256) {
            unsigned rec = bucket[e0 + i];
            int key = ((rec >> 21) & 63) * RR + ((rec >> 16) & 31);
            int p = atomicAdd(&bins[key], 1);
            stage[p] = rec & 0x1FFFFF;
        }
        __syncthreads();
        for (int i = t; i < n; i += 256) sorted[e0 + i] = stage[i];
    } else {
        for (int i = t; i < n; i += 256) {
            unsigned rec = bucket[e0 + i];
            int key = ((rec >> 21) & 63) * RR + ((rec >> 16) & 31);
            int p = atomicAdd(&bins[key], 1);
            sorted[e0 + p] = rec & 0x1FFFFF;
        }
    }
}

// ---------------- layer 1: wave-per-dst register gather ----------------
// lane = g*4+q : 16 edges in flight, each edge's 64B w1 row split across 4 lanes

__global__ __launch_bounds__(256) void layer1_k(
        const unsigned* __restrict__ sorted, const int* __restrict__ off,
        const float* __restrict__ inv, const float4* __restrict__ w1v,
        const float4* __restrict__ root1v, const float4* __restrict__ bias1v,
        float4* __restrict__ hv) {
    int d = (blockIdx.x * blockDim.x + threadIdx.x) >> 6;
    if (d >= NN) return;
    int lane = threadIdx.x & 63;
    int q = lane & 3;
    int b0 = off[d], b1 = off[d + 1];
    float4 acc = make_float4(0.f, 0.f, 0.f, 0.f);
    for (int i = b0 + (lane >> 2); i < b1; i += 16) {
        unsigned rec = sorted[i];
        int s = rec & 0xFFFF, r = (rec >> 16) & 31;
        float sc = inv[d * RR + r];
        float4 w = w1v[(size_t)(r * NN + s) * 4 + q];
        acc.x += w.x * sc; acc.y += w.y * sc; acc.z += w.z * sc; acc.w += w.w * sc;
    }
#pragma unroll
    for (int m = 4; m < 64; m <<= 1) {
        acc.x += __shfl_xor(acc.x, m); acc.y += __shfl_xor(acc.y, m);
        acc.z += __shfl_xor(acc.z, m); acc.w += __shfl_xor(acc.w, m);
    }
    if (lane < 4) {
        float4 rt = root1v[d * 4 + lane];
        float4 bs = bias1v[lane];
        float4 o;
        o.x = fmaxf(acc.x + rt.x + bs.x, 0.f);
        o.y = fmaxf(acc.y + rt.y + bs.y, 0.f);
        o.z = fmaxf(acc.z + rt.z + bs.z, 0.f);
        o.w = fmaxf(acc.w + rt.w + bs.w, 0.f);
        hv[d * 4 + lane] = o;
    }
}

// ---------------- layer 2: wave-per-dst + fused epilogue ----------------
// lane = sub*16+f : 4 edges in flight x 16 channels; 8 class accumulators/lane

__global__ __launch_bounds__(256) void layer2_k(
        const unsigned* __restrict__ sorted, const int* __restrict__ off,
        const float* __restrict__ inv, const float* __restrict__ h,
        const float* __restrict__ w2, const float* __restrict__ root2,
        const float* __restrict__ bias2, float* __restrict__ out) {
    int d = (blockIdx.x * blockDim.x + threadIdx.x) >> 6;
    if (d >= NN) return;
    int lane = threadIdx.x & 63;
    int sub = lane >> 4, f = lane & 15;
    int b0 = off[d], b1 = off[d + 1];
    float4 alo = make_float4(0.f, 0.f, 0.f, 0.f);
    float4 ahi = make_float4(0.f, 0.f, 0.f, 0.f);
    for (int i = b0 + sub; i < b1; i += 4) {
        unsigned rec = sorted[i];
        int s = rec & 0xFFFF, r = (rec >> 16) & 31;
        float p = h[s * HH + f] * inv[d * RR + r];
        const float4* w = (const float4*)(w2 + (r * HH + f) * CC);
        float4 wlo = w[0], whi = w[1];
        alo.x += p * wlo.x; alo.y += p * wlo.y; alo.z += p * wlo.z; alo.w += p * wlo.w;
        ahi.x += p * whi.x; ahi.y += p * whi.y; ahi.z += p * whi.z; ahi.w += p * whi.w;
    }
#pragma unroll
    for (int m = 1; m < 64; m <<= 1) {
        alo.x += __shfl_xor(alo.x, m); alo.y += __shfl_xor(alo.y, m);
        alo.z += __shfl_xor(alo.z, m); alo.w += __shfl_xor(alo.w, m);
        ahi.x += __shfl_xor(ahi.x, m); ahi.y += __shfl_xor(ahi.y, m);
        ahi.z += __shfl_xor(ahi.z, m); ahi.w += __shfl_xor(ahi.w, m);
    }
    if (lane == 0) {
        float v[CC] = {alo.x, alo.y, alo.z, alo.w, ahi.x, ahi.y, ahi.z, ahi.w};
        float hd[HH];
        const float4* hvp = (const float4*)(h + d * HH);
#pragma unroll
        for (int k = 0; k < 4; ++k) {
            float4 t4 = hvp[k];
            hd[k * 4 + 0] = t4.x; hd[k * 4 + 1] = t4.y;
            hd[k * 4 + 2] = t4.z; hd[k * 4 + 3] = t4.w;
        }
#pragma unroll
        for (int c = 0; c < CC; ++c) v[c] += bias2[c];
#pragma unroll
        for (int ff = 0; ff < HH; ++ff) {
            float hf = hd[ff];
#pragma unroll
            for (int c = 0; c < CC; ++c) v[c] += hf * root2[ff * CC + c];
        }
        float m0 = v[0];
#pragma unroll
        for (int c = 1; c < CC; ++c) m0 = fmaxf(m0, v[c]);
        float ssum = 0.f;
#pragma unroll
        for (int c = 0; c < CC; ++c) ssum += expf(v[c] - m0);
        float z = m0 + logf(ssum);
        float4* ov = (float4*)(out + d * CC);
        ov[0] = make_float4(v[0] - z, v[1] - z, v[2] - z, v[3] - z);
        ov[1] = make_float4(v[4] - z, v[5] - z, v[6] - z, v[7] - z);
    }
}

// ---------------- launch ----------------

extern "C" void kernel_launch(void* const* d_in, const int* in_sizes, int n_in,
                              void* d_out, int out_size, void* d_ws, size_t ws_size,
                              hipStream_t stream) {
    const int*   edge_index = (const int*)d_in[0];
    const int*   edge_type  = (const int*)d_in[1];
    const float* weight1    = (const float*)d_in[2];
    const float* root1      = (const float*)d_in[3];
    const float* bias1      = (const float*)d_in[4];
    const float* weight2    = (const float*)d_in[5];
    const float* root2      = (const float*)d_in[6];
    const float* bias2      = (const float*)d_in[7];
    float* out = (float*)d_out;

    const int E = in_sizes[1];
    const int* src = edge_index;
    const int* dst = edge_index + E;

    char* p = (char*)d_ws;
    auto alloc = [&](size_t bytes) -> void* {
        void* r = (void*)p; p += (bytes + 255) & ~(size_t)255; return r;
    };
    int*      hist   = (int*)     alloc(sizeof(int) * (size_t)G * NB);
    int*      pos    = (int*)     alloc(sizeof(int) * (size_t)G * NB);
    int*      btot   = (int*)     alloc(sizeof(int) * NB);
    int*      boff   = (int*)     alloc(sizeof(int) * (NB + 1));
    int*      off    = (int*)     alloc(sizeof(int) * (NN + 1));
    unsigned* bucket = (unsigned*)alloc(sizeof(unsigned) * (size_t)E);
    unsigned* sorted = (unsigned*)alloc(sizeof(unsigned) * (size_t)E);
    float*    inv    = (float*)   alloc(sizeof(float) * (size_t)NN * RR);
    float*    h      = (float*)   alloc(sizeof(float) * (size_t)NN * HH);
    (void)ws_size;

    hist_k<<<G, 256, 0, stream>>>(dst, hist, E);
    scanA_k<<<NB, 256, 0, stream>>>(hist, btot);
    scanB_k<<<1, 1024, 0, stream>>>(btot, boff);
    scanC_k<<<NB, 256, 0, stream>>>(hist, boff, pos);
    scatter2_k<<<G, 256, 0, stream>>>(src, dst, edge_type, pos, bucket, E);
    sortfin_k<<<NB, 256, 0, stream>>>(bucket, boff, sorted, off, inv);

    int nblk = (NN * 64 + 255) / 256;   // one wave per dst
    layer1_k<<<nblk, 256, 0, stream>>>(sorted, off, inv, (const float4*)weight1,
                                       (const float4*)root1, (const float4*)bias1,
                                       (float4*)h);
    layer2_k<<<nblk, 256, 0, stream>>>(sorted, off, inv, h, weight2, root2,
                                       bias2, out);
}